// Round 9
// baseline (258.968 us; speedup 1.0000x reference)
//
#include <hip/hip_runtime.h>

typedef __attribute__((ext_vector_type(8))) short bf16x8;  // 8 bf16 = 4 VGPRs (MFMA A/B frag)
typedef __attribute__((ext_vector_type(4))) float f32x4;   // MFMA C/D frag

constexpr int Dm  = 1024;    // d_model
constexpr int NH  = 16;      // heads
constexpr int HD  = 64;      // head dim
constexpr int SQ  = 2048;    // seq len
constexpr int BB  = 2;       // batch
constexpr int MM  = BB * SQ; // 4096 rows

// fp32 -> bf16 bits, round-to-nearest-even (finite values only)
__device__ __forceinline__ unsigned short f2bf(float f) {
    unsigned int u = __float_as_uint(f);
    u += 0x7FFFu + ((u >> 16) & 1u);
    return (unsigned short)(u >> 16);
}

// async global(16B) -> LDS; LDS placement = wave-uniform base + lane*16 [m97/m104]
__device__ __forceinline__ void gld16(const void* g, void* l) {
    __builtin_amdgcn_global_load_lds(
        (const __attribute__((address_space(1))) void*)g,
        (__attribute__((address_space(3))) void*)l, 16, 0, 0);
}

// ---------------------------------------------------------------------------
// One-shot cast of x + 4 weight matrices to bf16.
// ---------------------------------------------------------------------------
__global__ void cast_all(const float4* __restrict__ x,  const float4* __restrict__ qw,
                         const float4* __restrict__ kw, const float4* __restrict__ vw,
                         const float4* __restrict__ ow,
                         uint2* __restrict__ xb,  uint2* __restrict__ qwb,
                         uint2* __restrict__ kwb, uint2* __restrict__ vwb,
                         uint2* __restrict__ owb)
{
    int i = blockIdx.x * 256 + threadIdx.x;
    const float4* src; uint2* dst; int off;
    if      (i < 1048576) { src = x;  dst = xb;  off = i; }
    else if (i < 1310720) { src = qw; dst = qwb; off = i - 1048576; }
    else if (i < 1572864) { src = kw; dst = kwb; off = i - 1310720; }
    else if (i < 1835008) { src = vw; dst = vwb; off = i - 1572864; }
    else                  { src = ow; dst = owb; off = i - 1835008; }
    float4 v = src[off];
    uint2 o;
    o.x = (unsigned)f2bf(v.x) | ((unsigned)f2bf(v.y) << 16);
    o.y = (unsigned)f2bf(v.z) | ((unsigned)f2bf(v.w) << 16);
    dst[off] = o;
}

// ---------------------------------------------------------------------------
// m97-style MFMA GEMM core (unchanged from r8): 128x128 tile, BK=32, 4 waves.
// ---------------------------------------------------------------------------
template<typename EPI>
__device__ __forceinline__ void gemm_core(const unsigned short* __restrict__ A,
                                          const unsigned short* __restrict__ W,
                                          const float* __restrict__ bias,
                                          int n0, int m0, EPI epi)
{
    __shared__ unsigned short As[128 * 32];
    __shared__ unsigned short Ws[128 * 32];
    const int t    = threadIdx.x;
    const int lane = t & 63, w = t >> 6;
    const int lm   = lane & 15, quad = lane >> 4;
    const int wm   = w & 1, wn = w >> 1;

    const f32x4 fz = {0.f, 0.f, 0.f, 0.f};
    f32x4 acc[4][4];
#pragma unroll
    for (int mi = 0; mi < 4; ++mi)
#pragma unroll
        for (int ni = 0; ni < 4; ++ni) acc[mi][ni] = fz;

    float bsv[4];
#pragma unroll
    for (int ni = 0; ni < 4; ++ni) bsv[ni] = bias[n0 + wn * 64 + ni * 16 + lm];

    const int r0 = t >> 2,         ks0 = t & 3;
    const int r1 = (t + 256) >> 2, ks1 = (t + 256) & 3;

    for (int k0 = 0; k0 < 1024; k0 += 32) {
        __syncthreads();
        gld16(A + (size_t)(m0 + r0) * 1024 + k0 + ks0 * 8, &As[t * 8]);
        gld16(A + (size_t)(m0 + r1) * 1024 + k0 + ks1 * 8, &As[(t + 256) * 8]);
        gld16(W + (size_t)(n0 + r0) * 1024 + k0 + ks0 * 8, &Ws[t * 8]);
        gld16(W + (size_t)(n0 + r1) * 1024 + k0 + ks1 * 8, &Ws[(t + 256) * 8]);
        __syncthreads();

        bf16x8 af[4], bfr[4];
#pragma unroll
        for (int mi = 0; mi < 4; ++mi)
            af[mi] = *(const bf16x8*)&As[(wm * 64 + mi * 16 + lm) * 32 + quad * 8];
#pragma unroll
        for (int ni = 0; ni < 4; ++ni)
            bfr[ni] = *(const bf16x8*)&Ws[(wn * 64 + ni * 16 + lm) * 32 + quad * 8];
#pragma unroll
        for (int mi = 0; mi < 4; ++mi)
#pragma unroll
            for (int ni = 0; ni < 4; ++ni)
                acc[mi][ni] = __builtin_amdgcn_mfma_f32_16x16x32_bf16(
                                  af[mi], bfr[ni], acc[mi][ni], 0, 0, 0);
    }

    // C/D layout: col = lane&15, row = quad*4 + reg
#pragma unroll
    for (int mi = 0; mi < 4; ++mi)
#pragma unroll
        for (int ni = 0; ni < 4; ++ni)
#pragma unroll
            for (int r = 0; r < 4; ++r) {
                const int m = m0 + wm * 64 + mi * 16 + quad * 4 + r;
                const int n = n0 + wn * 64 + ni * 16 + lm;
                epi(m, n, acc[mi][ni][r] + bsv[ni]);
            }
}

__global__ __launch_bounds__(256) void gemm_qkv(
    const unsigned short* __restrict__ xb,
    const unsigned short* __restrict__ qwb, const float* __restrict__ qb,
    const unsigned short* __restrict__ kwb, const float* __restrict__ kb,
    const unsigned short* __restrict__ vwb, const float* __restrict__ vb,
    unsigned short* __restrict__ Qb, unsigned short* __restrict__ Kb,
    unsigned short* __restrict__ Vb)
{
    const int z = blockIdx.z;
    const unsigned short* W = (z == 0) ? qwb : (z == 1) ? kwb : vwb;
    const float* bias       = (z == 0) ? qb  : (z == 1) ? kb  : vb;
    unsigned short* dst     = (z == 0) ? Qb  : (z == 1) ? Kb  : Vb;
    const int n0 = blockIdx.x * 128, m0 = blockIdx.y * 128;
    const bool vt = (z == 2);

    gemm_core(xb, W, bias, n0, m0, [&](int m, int n, float v) {
        const int b = m >> 11, s = m & 2047, h = n >> 6, hd = n & 63;
        const size_t idx = vt ? ((size_t)((b * NH + h) * 64 + hd) * SQ + s)
                              : ((size_t)((b * NH + h) * SQ + s) * 64 + hd);
        dst[idx] = f2bf(v);
    });
}

__global__ __launch_bounds__(256) void gemm_out(
    const unsigned short* __restrict__ Ab, const unsigned short* __restrict__ owb,
    const float* __restrict__ ob, float* __restrict__ out)
{
    const int n0 = blockIdx.x * 128, m0 = blockIdx.y * 128;
    gemm_core(Ab, owb, ob, n0, m0, [&](int m, int n, float v) {
        out[(size_t)m * 1024 + n] = v;
    });
}

// ---------------------------------------------------------------------------
// Attention v2. Block = (b,h) x 64q; 4 waves in 2x2 split: wq = q-half(32q),
// wk = key-half(32k). Q frags in registers. K/V staged via global_load_lds
// into frag-linear 16x32 blocks (LDS slot = lane*16B -> conflict-free reads,
// zero ds_write staging). E strips wave-private. Cross-wk O reduce at end.
// ---------------------------------------------------------------------------
constexpr int STE = 40;   // E strip row stride (ushorts); 80B, 16B-aligned

__global__ __launch_bounds__(256) void attn_mfma(const unsigned short* __restrict__ Qg,
                                                 const unsigned short* __restrict__ Kg,
                                                 const unsigned short* __restrict__ Vtg,
                                                 const float* __restrict__ esc,
                                                 const float* __restrict__ ebi,
                                                 unsigned short* __restrict__ Ab,
                                                 float* __restrict__ unc)
{
    // sm: Ks 8*512 | Vts 8*512 | Es 4*32*STE   (ushorts)
    // unions: Ored (f32[2][32][64]=16KB) over Ks+Vts; dredA (f32[4][32][16]=8KB) over Es
    __shared__ __align__(16) unsigned short sm[4096 + 4096 + 4 * 32 * STE];
    __shared__ float dinv[64];
    unsigned short* Ks  = sm;
    unsigned short* Vts = sm + 4096;
    unsigned short* Es  = sm + 8192;
    float* Ored  = (float*)sm;
    float* dredA = (float*)(sm + 8192);

    const int t    = threadIdx.x;
    const int lane = t & 63, w = t >> 6;
    const int lm   = lane & 15, quad = lane >> 4;
    const int wq   = w & 1, wk = w >> 1;
    const int qt   = blockIdx.x & 31;
    const int bh   = blockIdx.x >> 5;
    const int q0   = qt * 64;

    const float scale = esc[0];
    const float bias1 = 1.0f + ebi[0];

    // Q fragments in registers: qa[mi][kc], A[m=lm][k=quad*8+j]
    bf16x8 qa[2][2];
#pragma unroll
    for (int mi = 0; mi < 2; ++mi)
#pragma unroll
        for (int kc = 0; kc < 2; ++kc)
            qa[mi][kc] = *(const bf16x8*)(Qg +
                (size_t)(bh * SQ + q0 + wq * 32 + mi * 16 + lm) * 64 + kc * 32 + quad * 8);

    const f32x4 fz = {0.f, 0.f, 0.f, 0.f};
    f32x4 acc[2][4];
#pragma unroll
    for (int mi = 0; mi < 2; ++mi)
#pragma unroll
        for (int nd = 0; nd < 4; ++nd) acc[mi][nd] = fz;
    float drow[2][4] = {};

    const unsigned short* EsW = Es + w * 32 * STE;   // wave-private strip

    for (int kt = 0; kt < 32; ++kt) {
        __syncthreads();   // prev iter's Ks/Vts readers done
        {
            // wave w stages K blocks (rows w*16..+16) and V blocks (d rows w*16..+16)
            const unsigned short* kg = Kg + (size_t)(bh * SQ + kt * 64) * 64
                                     + (size_t)(w * 16 + lm) * 64 + quad * 8;
            gld16(kg,      &Ks[(w * 2 + 0) * 512]);
            gld16(kg + 32, &Ks[(w * 2 + 1) * 512]);
            const unsigned short* vg = Vtg + (size_t)bh * 64 * SQ + kt * 64
                                     + (size_t)(w * 16 + lm) * SQ + quad * 8;
            gld16(vg,      &Vts[(w * 2 + 0) * 512]);
            gld16(vg + 32, &Vts[(w * 2 + 1) * 512]);
        }
        __syncthreads();

        // S = Q K^T on wave's 32q x 32k quadrant
        bf16x8 kbf[2][2];
#pragma unroll
        for (int ni = 0; ni < 2; ++ni)
#pragma unroll
            for (int kc = 0; kc < 2; ++kc)
                kbf[ni][kc] = *(const bf16x8*)&Ks[((wk * 2 + ni) * 2 + kc) * 512 + lane * 8];

#pragma unroll
        for (int mi = 0; mi < 2; ++mi)
#pragma unroll
            for (int ni = 0; ni < 2; ++ni) {
                f32x4 s = fz;
#pragma unroll
                for (int kc = 0; kc < 2; ++kc)
                    s = __builtin_amdgcn_mfma_f32_16x16x32_bf16(qa[mi][kc], kbf[ni][kc], s, 0, 0, 0);
#pragma unroll
                for (int r = 0; r < 4; ++r) {
                    float ev = __expf(s[r] * 0.125f) * scale + bias1;
                    drow[mi][r] += ev;
                    ((unsigned short*)EsW)[(mi * 16 + quad * 4 + r) * STE + ni * 16 + lm] = f2bf(ev);
                }
            }
        // no barrier: Es strip is wave-private (compiler inserts lgkmcnt waits)

        // acc += E V on wave's key-half (K=32 single step)
        bf16x8 ea[2];
#pragma unroll
        for (int mi = 0; mi < 2; ++mi)
            ea[mi] = *(const bf16x8*)&EsW[(mi * 16 + lm) * STE + quad * 8];
#pragma unroll
        for (int nd = 0; nd < 4; ++nd) {
            bf16x8 vbf = *(const bf16x8*)&Vts[(nd * 2 + wk) * 512 + lane * 8];
#pragma unroll
            for (int mi = 0; mi < 2; ++mi)
                acc[mi][nd] = __builtin_amdgcn_mfma_f32_16x16x32_bf16(ea[mi], vbf, acc[mi][nd], 0, 0, 0);
        }
    }

    // ---- cross-wave reduction (reuses Ks/Vts as Ored, Es as dredA) ----
    __syncthreads();
    if (wk == 1) {
#pragma unroll
        for (int mi = 0; mi < 2; ++mi)
#pragma unroll
            for (int nd = 0; nd < 4; ++nd)
#pragma unroll
                for (int r = 0; r < 4; ++r)
                    Ored[wq * 2048 + (mi * 16 + quad * 4 + r) * 64 + nd * 16 + lm] = acc[mi][nd][r];
    }
#pragma unroll
    for (int mi = 0; mi < 2; ++mi)
#pragma unroll
        for (int r = 0; r < 4; ++r)
            dredA[w * 512 + (mi * 16 + quad * 4 + r) * 16 + lm] = drow[mi][r];
    __syncthreads();

    if (t < 64) {
        const int wq2 = t >> 5, ql = t & 31;
        float d = 0.f;
#pragma unroll
        for (int k2 = 0; k2 < 2; ++k2)
#pragma unroll
            for (int c = 0; c < 16; ++c)
                d += dredA[(k2 * 2 + wq2) * 512 + ql * 16 + c];
        unc[(size_t)bh * SQ + q0 + t] = (float)SQ / d;
        dinv[t] = 1.0f / d;
    }
    __syncthreads();

    if (wk == 0) {
        const int b = bh >> 4, h = bh & 15;
#pragma unroll
        for (int mi = 0; mi < 2; ++mi)
#pragma unroll
            for (int nd = 0; nd < 4; ++nd)
#pragma unroll
                for (int r = 0; r < 4; ++r) {
                    const int ql = mi * 16 + quad * 4 + r;
                    const int q  = wq * 32 + ql;
                    const float v = (acc[mi][nd][r] + Ored[wq * 2048 + ql * 64 + nd * 16 + lm])
                                    * dinv[q];
                    Ab[(size_t)(b * SQ + q0 + q) * Dm + h * 64 + nd * 16 + lm] = f2bf(v);
                }
    }
}

extern "C" void kernel_launch(void* const* d_in, const int* in_sizes, int n_in,
                              void* d_out, int out_size, void* d_ws, size_t ws_size,
                              hipStream_t stream)
{
    const float* x   = (const float*)d_in[0];
    const float* qw  = (const float*)d_in[1];
    const float* qb  = (const float*)d_in[2];
    const float* kw  = (const float*)d_in[3];
    const float* kb  = (const float*)d_in[4];
    const float* vw  = (const float*)d_in[5];
    const float* vb  = (const float*)d_in[6];
    const float* ow  = (const float*)d_in[7];
    const float* ob  = (const float*)d_in[8];
    const float* esc = (const float*)d_in[9];
    const float* ebi = (const float*)d_in[10];

    float* out = (float*)d_out;                 // output 0: [B,S,D] fp32 (16 MB)
    float* unc = out + (size_t)MM * Dm;         // output 1: [B,H,S] fp32

    // ws (24 MB): xb 8MB @0 (reused as Ab) | qwb/kwb/vwb/owb 2MB @8/10/12/14MB | Vb 8MB @16MB
    unsigned short* xb  = (unsigned short*)d_ws;
    unsigned short* qwb = (unsigned short*)((char*)d_ws + (8u  << 20));
    unsigned short* kwb = (unsigned short*)((char*)d_ws + (10u << 20));
    unsigned short* vwb = (unsigned short*)((char*)d_ws + (12u << 20));
    unsigned short* owb = (unsigned short*)((char*)d_ws + (14u << 20));
    unsigned short* Vb  = (unsigned short*)((char*)d_ws + (16u << 20));
    unsigned short* Ab  = xb;                   // xb dead after QKV GEMMs

    // Q,K tiles live in d_out's output-0 region (dead until gemm_out writes it last)
    unsigned short* Qb = (unsigned short*)d_out;
    unsigned short* Kb = Qb + (size_t)MM * Dm;

    cast_all<<<dim3(2097152 / 256), dim3(256), 0, stream>>>(
        (const float4*)x, (const float4*)qw, (const float4*)kw,
        (const float4*)vw, (const float4*)ow,
        (uint2*)xb, (uint2*)qwb, (uint2*)kwb, (uint2*)vwb, (uint2*)owb);

    gemm_qkv<<<dim3(Dm / 128, MM / 128, 3), dim3(256), 0, stream>>>(
        xb, qwb, qb, kwb, kb, vwb, vb, Qb, Kb, Vb);

    attn_mfma<<<dim3(BB * NH * (SQ / 64)), dim3(256), 0, stream>>>(
        Qb, Kb, Vb, esc, ebi, Ab, unc);

    gemm_out<<<dim3(Dm / 128, MM / 128), dim3(256), 0, stream>>>(Ab, owb, ob, out);
}

// Round 11
// 224.521 us; speedup vs baseline: 1.1534x; 1.1534x over previous
//
#include <hip/hip_runtime.h>

typedef __attribute__((ext_vector_type(8))) short bf16x8;  // 8 bf16 = 4 VGPRs (MFMA A/B frag)
typedef __attribute__((ext_vector_type(4))) float f32x4;   // MFMA C/D frag
typedef unsigned short ushort_t;

constexpr int Dm  = 1024;    // d_model
constexpr int NH  = 16;      // heads
constexpr int HD  = 64;      // head dim
constexpr int SQ  = 2048;    // seq len
constexpr int BB  = 2;       // batch
constexpr int MM  = BB * SQ; // 4096 rows

// fp32 -> bf16 bits, round-to-nearest-even (finite values only)
__device__ __forceinline__ ushort_t f2bf(float f) {
    unsigned int u = __float_as_uint(f);
    u += 0x7FFFu + ((u >> 16) & 1u);
    return (ushort_t)(u >> 16);
}

// async global(16B) -> LDS; lane l lands at readfirstlane(dst)+l*16 [m97/m104]
__device__ __forceinline__ void gld16(const void* g, void* l) {
    __builtin_amdgcn_global_load_lds(
        (const __attribute__((address_space(1))) void*)g,
        (__attribute__((address_space(3))) void*)l, 16, 0, 0);
}

// ---------------------------------------------------------------------------
// One-shot cast of x + 4 weight matrices to bf16.
// ---------------------------------------------------------------------------
__global__ void cast_all(const float4* __restrict__ x,  const float4* __restrict__ qw,
                         const float4* __restrict__ kw, const float4* __restrict__ vw,
                         const float4* __restrict__ ow,
                         uint2* __restrict__ xb,  uint2* __restrict__ qwb,
                         uint2* __restrict__ kwb, uint2* __restrict__ vwb,
                         uint2* __restrict__ owb)
{
    int i = blockIdx.x * 256 + threadIdx.x;
    const float4* src; uint2* dst; int off;
    if      (i < 1048576) { src = x;  dst = xb;  off = i; }
    else if (i < 1310720) { src = qw; dst = qwb; off = i - 1048576; }
    else if (i < 1572864) { src = kw; dst = kwb; off = i - 1310720; }
    else if (i < 1835008) { src = vw; dst = vwb; off = i - 1572864; }
    else                  { src = ow; dst = owb; off = i - 1835008; }
    float4 v = src[off];
    uint2 o;
    o.x = (unsigned)f2bf(v.x) | ((unsigned)f2bf(v.y) << 16);
    o.y = (unsigned)f2bf(v.z) | ((unsigned)f2bf(v.w) << 16);
    dst[off] = o;
}

// ---------------------------------------------------------------------------
// Double-buffered single-barrier MFMA GEMM core.
// C = A(bf16)[M,1024] @ W(bf16,[N,1024])^T + bias. Tile TM x 128, BK=32,
// 256 thr = 4 waves (2x2). Staging via global_load_lds dwordx4, lane-linear.
// Pipeline: barrier; prefetch k+1 -> buf^1; compute buf (loads drain at the
// NEXT barrier, after a full compute phase of latency hiding).
// ---------------------------------------------------------------------------
template<int TM, typename EPI>
__device__ __forceinline__ void gemm_core(const ushort_t* __restrict__ A,
                                          const ushort_t* __restrict__ W,
                                          const float* __restrict__ bias,
                                          int n0, int m0, EPI epi)
{
    constexpr int AF = TM / 32;            // A frags per wave (wave tile = TM/2 rows)
    __shared__ ushort_t As[2][TM * 32];
    __shared__ ushort_t Ws[2][128 * 32];
    const int t    = threadIdx.x;
    const int lane = t & 63, w = t >> 6;
    const int lm   = lane & 15, quad = lane >> 4;
    const int wm   = w & 1, wn = w >> 1;

    const f32x4 fz = {0.f, 0.f, 0.f, 0.f};
    f32x4 acc[AF][4];
#pragma unroll
    for (int mi = 0; mi < AF; ++mi)
#pragma unroll
        for (int ni = 0; ni < 4; ++ni) acc[mi][ni] = fz;

    float bsv[4];
#pragma unroll
    for (int ni = 0; ni < 4; ++ni) bsv[ni] = bias[n0 + wn * 64 + ni * 16 + lm];

    auto stage = [&](int k0, int b) {
#pragma unroll
        for (int j = 0; j < TM / 64; ++j) {          // A: TM*4 slots of 16B
            int s = t + 256 * j;
            gld16(A + (size_t)(m0 + (s >> 2)) * 1024 + k0 + (s & 3) * 8, &As[b][s * 8]);
        }
#pragma unroll
        for (int j = 0; j < 2; ++j) {                // W: 512 slots
            int s = t + 256 * j;
            gld16(W + (size_t)(n0 + (s >> 2)) * 1024 + k0 + (s & 3) * 8, &Ws[b][s * 8]);
        }
    };

    stage(0, 0);
    int cur = 0;
    for (int k0 = 0; k0 < 1024; k0 += 32) {
        __syncthreads();              // drains buf[cur] loads; frees buf[cur^1]
        if (k0 + 32 < 1024) stage(k0 + 32, cur ^ 1);

        bf16x8 af[AF], bfr[4];
#pragma unroll
        for (int mi = 0; mi < AF; ++mi)
            af[mi] = *(const bf16x8*)&As[cur][(wm * (TM / 2) + mi * 16 + lm) * 32 + quad * 8];
#pragma unroll
        for (int ni = 0; ni < 4; ++ni)
            bfr[ni] = *(const bf16x8*)&Ws[cur][(wn * 64 + ni * 16 + lm) * 32 + quad * 8];
#pragma unroll
        for (int mi = 0; mi < AF; ++mi)
#pragma unroll
            for (int ni = 0; ni < 4; ++ni)
                acc[mi][ni] = __builtin_amdgcn_mfma_f32_16x16x32_bf16(
                                  af[mi], bfr[ni], acc[mi][ni], 0, 0, 0);
        cur ^= 1;
    }

    // C/D layout: col = lane&15, row = quad*4 + reg
#pragma unroll
    for (int mi = 0; mi < AF; ++mi)
#pragma unroll
        for (int ni = 0; ni < 4; ++ni)
#pragma unroll
            for (int r = 0; r < 4; ++r) {
                const int m = m0 + wm * (TM / 2) + mi * 16 + quad * 4 + r;
                const int n = n0 + wn * 64 + ni * 16 + lm;
                epi(m, n, acc[mi][ni][r] + bsv[ni]);
            }
}

__global__ __launch_bounds__(256) void gemm_qkv(
    const ushort_t* __restrict__ xb,
    const ushort_t* __restrict__ qwb, const float* __restrict__ qb,
    const ushort_t* __restrict__ kwb, const float* __restrict__ kb,
    const ushort_t* __restrict__ vwb, const float* __restrict__ vb,
    ushort_t* __restrict__ Qb, ushort_t* __restrict__ Kb, ushort_t* __restrict__ Vb)
{
    const int z = blockIdx.z;
    const ushort_t* W   = (z == 0) ? qwb : (z == 1) ? kwb : vwb;
    const float*    bias = (z == 0) ? qb  : (z == 1) ? kb  : vb;
    ushort_t*       dst  = (z == 0) ? Qb  : (z == 1) ? Kb  : Vb;
    const int n0 = blockIdx.x * 128, m0 = blockIdx.y * 128;
    const bool vt = (z == 2);

    gemm_core<128>(xb, W, bias, n0, m0, [&](int m, int n, float v) {
        const int b = m >> 11, s = m & 2047, h = n >> 6, hd = n & 63;
        const size_t idx = vt ? ((size_t)((b * NH + h) * 64 + hd) * SQ + s)
                              : ((size_t)((b * NH + h) * SQ + s) * 64 + hd);
        dst[idx] = f2bf(v);
    });
}

__global__ __launch_bounds__(256) void gemm_out(
    const ushort_t* __restrict__ Ab, const ushort_t* __restrict__ owb,
    const float* __restrict__ ob, float* __restrict__ out)
{
    const int n0 = blockIdx.x * 128, m0 = blockIdx.y * 64;
    gemm_core<64>(Ab, owb, ob, n0, m0, [&](int m, int n, float v) {
        out[(size_t)m * 1024 + n] = v;
    });
}

// ---------------------------------------------------------------------------
// Attention v3. Block = (b,h) x 64q; 4 waves, each owns 16 q-rows x all keys.
// Q frags in registers. K/V double-buffered via global_load_lds (frag-linear
// blocks, conflict-free); ONE barrier per kt. E handled in 32-key halves via
// a wave-private LDS strip (no barrier). Denominator: __shfl_xor butterfly.
// ---------------------------------------------------------------------------
__global__ __launch_bounds__(256) void attn_mfma(const ushort_t* __restrict__ Qg,
                                                 const ushort_t* __restrict__ Kg,
                                                 const ushort_t* __restrict__ Vtg,
                                                 const float* __restrict__ esc,
                                                 const float* __restrict__ ebi,
                                                 ushort_t* __restrict__ Ab,
                                                 float* __restrict__ unc)
{
    __shared__ __align__(16) ushort_t Kbuf[2][4096];   // 8 blocks x 512 (16 keys x 32 d)
    __shared__ __align__(16) ushort_t Vbuf[2][4096];   // 8 blocks x 512 (16 d x 32 keys)
    __shared__ __align__(16) ushort_t Es[4][16 * 40];  // wave strip 16q x 32k, stride 40

    const int t    = threadIdx.x;
    const int lane = t & 63, w = t >> 6;
    const int lm   = lane & 15, quad = lane >> 4;
    const int qt   = blockIdx.x & 31;
    const int bh   = blockIdx.x >> 5;
    const int q0   = qt * 64;

    const float scale = esc[0];
    const float bias1 = 1.0f + ebi[0];

    // Q frags in registers: wave strip rows q = q0 + w*16 + lm
    bf16x8 qa[2];
#pragma unroll
    for (int kc = 0; kc < 2; ++kc)
        qa[kc] = *(const bf16x8*)(Qg + (size_t)(bh * SQ + q0 + w * 16 + lm) * 64
                                  + kc * 32 + quad * 8);

    const f32x4 fz = {0.f, 0.f, 0.f, 0.f};
    f32x4 acc[4];
#pragma unroll
    for (int nd = 0; nd < 4; ++nd) acc[nd] = fz;
    float drow[4] = {0.f, 0.f, 0.f, 0.f};

    // wave w stages K keys w*16..+16 (blocks (w,c)) and V d-rows w*16..+16
    auto stage = [&](int kt, int b) {
        const ushort_t* kg = Kg + (size_t)(bh * SQ + kt * 64 + w * 16 + lm) * 64 + quad * 8;
        gld16(kg,      &Kbuf[b][(w * 2 + 0) * 512]);
        gld16(kg + 32, &Kbuf[b][(w * 2 + 1) * 512]);
        const ushort_t* vg = Vtg + (size_t)bh * 64 * SQ + (size_t)(w * 16 + lm) * SQ
                           + kt * 64 + quad * 8;
        gld16(vg,      &Vbuf[b][(w * 2 + 0) * 512]);
        gld16(vg + 32, &Vbuf[b][(w * 2 + 1) * 512]);
    };

    stage(0, 0);
    int cur = 0;
    for (int kt = 0; kt < 32; ++kt) {
        __syncthreads();              // drains buf[cur]; frees buf[cur^1]
        if (kt + 1 < 32) stage(kt + 1, cur ^ 1);
        const ushort_t* Kc = Kbuf[cur];
        const ushort_t* Vc = Vbuf[cur];
        ushort_t* EsW = &Es[w][0];

#pragma unroll
        for (int hc = 0; hc < 2; ++hc) {
            // S = Q K^T for keys hc*32..+32 (key group g = hc*2+ni, d-half kc)
#pragma unroll
            for (int ni = 0; ni < 2; ++ni) {
                f32x4 s = fz;
#pragma unroll
                for (int kc = 0; kc < 2; ++kc) {
                    bf16x8 kb = *(const bf16x8*)&Kc[((hc * 2 + ni) * 2 + kc) * 512 + lane * 8];
                    s = __builtin_amdgcn_mfma_f32_16x16x32_bf16(qa[kc], kb, s, 0, 0, 0);
                }
#pragma unroll
                for (int r = 0; r < 4; ++r) {
                    float ev = __expf(s[r] * 0.125f) * scale + bias1;
                    drow[r] += ev;
                    EsW[(quad * 4 + r) * 40 + ni * 16 + lm] = f2bf(ev);
                }
            }
            // acc += E V over this key half (K=32): A = E strip, B = Vt block (nd,hc)
            bf16x8 ea = *(const bf16x8*)&EsW[lm * 40 + quad * 8];
#pragma unroll
            for (int nd = 0; nd < 4; ++nd) {
                bf16x8 vb = *(const bf16x8*)&Vc[(nd * 2 + hc) * 512 + lane * 8];
                acc[nd] = __builtin_amdgcn_mfma_f32_16x16x32_bf16(ea, vb, acc[nd], 0, 0, 0);
            }
        }
        cur ^= 1;
    }

    // denominator: butterfly over the 16 lm lanes (quad bits preserved)
#pragma unroll
    for (int r = 0; r < 4; ++r) {
        float d = drow[r];
        d += __shfl_xor(d, 1, 64);
        d += __shfl_xor(d, 2, 64);
        d += __shfl_xor(d, 4, 64);
        d += __shfl_xor(d, 8, 64);
        drow[r] = d;
    }
    if (lm == 0) {
#pragma unroll
        for (int r = 0; r < 4; ++r)
            unc[(size_t)bh * SQ + q0 + w * 16 + quad * 4 + r] = (float)SQ / drow[r];
    }

    const int b = bh >> 4, h = bh & 15;
    float di[4];
#pragma unroll
    for (int r = 0; r < 4; ++r) di[r] = 1.0f / drow[r];
#pragma unroll
    for (int nd = 0; nd < 4; ++nd)
#pragma unroll
        for (int r = 0; r < 4; ++r) {
            const int q = w * 16 + quad * 4 + r;
            Ab[(size_t)(b * SQ + q0 + q) * Dm + h * 64 + nd * 16 + lm]
                = f2bf(acc[nd][r] * di[r]);
        }
}

extern "C" void kernel_launch(void* const* d_in, const int* in_sizes, int n_in,
                              void* d_out, int out_size, void* d_ws, size_t ws_size,
                              hipStream_t stream)
{
    const float* x   = (const float*)d_in[0];
    const float* qw  = (const float*)d_in[1];
    const float* qb  = (const float*)d_in[2];
    const float* kw  = (const float*)d_in[3];
    const float* kb  = (const float*)d_in[4];
    const float* vw  = (const float*)d_in[5];
    const float* vb  = (const float*)d_in[6];
    const float* ow  = (const float*)d_in[7];
    const float* ob  = (const float*)d_in[8];
    const float* esc = (const float*)d_in[9];
    const float* ebi = (const float*)d_in[10];

    float* out = (float*)d_out;                 // output 0: [B,S,D] fp32 (16 MB)
    float* unc = out + (size_t)MM * Dm;         // output 1: [B,H,S] fp32

    // ws (24 MB): xb 8MB @0 (reused as Ab) | qwb/kwb/vwb/owb 2MB @8/10/12/14MB | Vb 8MB @16MB
    ushort_t* xb  = (ushort_t*)d_ws;
    ushort_t* qwb = (ushort_t*)((char*)d_ws + (8u  << 20));
    ushort_t* kwb = (ushort_t*)((char*)d_ws + (10u << 20));
    ushort_t* vwb = (ushort_t*)((char*)d_ws + (12u << 20));
    ushort_t* owb = (ushort_t*)((char*)d_ws + (14u << 20));
    ushort_t* Vb  = (ushort_t*)((char*)d_ws + (16u << 20));
    ushort_t* Ab  = xb;                         // xb dead after QKV GEMMs

    // Q,K tiles live in d_out's output-0 region (dead until gemm_out writes it last)
    ushort_t* Qb = (ushort_t*)d_out;
    ushort_t* Kb = Qb + (size_t)MM * Dm;

    cast_all<<<dim3(2097152 / 256), dim3(256), 0, stream>>>(
        (const float4*)x, (const float4*)qw, (const float4*)kw,
        (const float4*)vw, (const float4*)ow,
        (uint2*)xb, (uint2*)qwb, (uint2*)kwb, (uint2*)vwb, (uint2*)owb);

    gemm_qkv<<<dim3(Dm / 128, MM / 128, 3), dim3(256), 0, stream>>>(
        xb, qwb, qb, kwb, kb, vwb, vb, Qb, Kb, Vb);

    attn_mfma<<<dim3(BB * NH * (SQ / 64)), dim3(256), 0, stream>>>(
        Qb, Kb, Vb, esc, ebi, Ab, unc);

    gemm_out<<<dim3(Dm / 128, MM / 64), dim3(256), 0, stream>>>(Ab, owb, ob, out);
}